// Round 4
// baseline (308.443 us; speedup 1.0000x reference)
//
#include <hip/hip_runtime.h>

// GAE backward scan. B=4096 rows, T=2048 steps.
// R5: ONE WAVE PER ROW -- zero barriers, zero LDS.
// Evidence so far: R2 (65% occ) and R4 (28% occ) both sustain ~2.2 TB/s
// -> BW is decoupled from occupancy; the shared structure of R1-R4 is
// the inter-wave barrier, which couples each row's stores to the MAX of
// its 4-8 waves' load latencies (heavy tail under load) and serializes
// the LDS affine combine behind it.
// Here lane i owns contiguous elements [32i, 32i+32) of its row:
//   pass 1: fold loads into (c, delta, v); serial backward affine
//           (A = gae with zero carry, B = prod of decay) per lane;
//   6-level __shfl_down suffix-composition across 64 lanes;
//   gin = shfl_down(A,1)  (row carry is 0, lane 63 -> 0);
//   pass 2: re-run the serial recurrence seeded at gin, in place.
// 13 DS ops per row total, 4096 independent waves, whole grid resident
// in one generation -> kernel shape approaches a streaming copy.

constexpr float GAMMA = 0.99f;
constexpr float LMBDA = 0.95f;
constexpr float GL    = GAMMA * LMBDA;
constexpr int   T     = 2048;
constexpr int   TPB   = 256;
constexpr int   WPB   = TPB / 64;       // 4 waves (= 4 rows) per block
constexpr int   EPL   = T / 64;         // 32 elements per lane
constexpr int   NF4   = EPL / 4;        // 8 float4 groups per lane

typedef float f4 __attribute__((ext_vector_type(4)));

__global__ __launch_bounds__(TPB) void gae_kernel(
    const float* __restrict__ reward,
    const int*   __restrict__ term,
    const float* __restrict__ value,
    const float* __restrict__ next_value,
    float* __restrict__ adv_out,
    float* __restrict__ ret_out)
{
    const int lane = threadIdx.x & 63;
    const int wave = threadIdx.x >> 6;
    const int row  = blockIdx.x * WPB + wave;
    const size_t base = (size_t)row * T + (size_t)lane * EPL;

    // Load and immediately fold into the minimal working set:
    //   c[t]  = gamma*lambda*nd      (decay)
    //   d[t]  = r + gamma*nv*nd - v  (delta)
    //   v[t]  = value                (kept for ret = adv + v)
    // Peak live ~3 arrays of 32 + in-flight loads.
    float c[EPL], d[EPL], v[EPL];
    #pragma unroll
    for (int q = 0; q < NF4; ++q) {
        const size_t o = base + 4 * q;
        const f4   rv = *(const f4*  )(reward     + o);
        const int4 tv = *(const int4*)(term       + o);
        const f4   vv = *(const f4*  )(value      + o);
        const f4   nx = *(const f4*  )(next_value + o);
        const int ti[4] = {tv.x, tv.y, tv.z, tv.w};
        #pragma unroll
        for (int u = 0; u < 4; ++u) {
            const int   t  = 4 * q + u;
            const float nd = 1.f - (float)ti[u];
            v[t] = vv[u];
            c[t] = GL * nd;
            d[t] = fmaf(GAMMA * nx[u], nd, rv[u]) - vv[u];
        }
    }

    // Pass 1: per-lane backward affine with zero carry.
    // A = gae at segment start (carry 0), B = product of decays.
    float A, Bc;
    {
        float g = 0.f, p = 1.f;
        #pragma unroll
        for (int t = EPL - 1; t >= 0; --t) {
            g = fmaf(c[t], g, d[t]);
            p *= c[t];
        }
        A = g; Bc = p;
    }

    // Inclusive suffix-composition scan across the 64 lanes
    // (higher lane = later time; carry flows high->low).
    #pragma unroll
    for (int off = 1; off < 64; off <<= 1) {
        const float a2 = __shfl_down(A,  off, 64);
        const float b2 = __shfl_down(Bc, off, 64);
        if (lane + off < 64) {
            A  = fmaf(Bc, a2, A);
            Bc *= b2;
        }
    }

    // Carry entering this lane's segment = inclusive result of lane+1
    // evaluated at the row's right-boundary carry (= 0) -> just A.
    float gin = __shfl_down(A, 1, 64);
    if (lane == 63) gin = 0.f;

    // Pass 2: re-run the recurrence seeded at gin; adv written in place
    // over d (d[t] is dead once consumed).
    {
        float g = gin;
        #pragma unroll
        for (int t = EPL - 1; t >= 0; --t) {
            g = fmaf(c[t], g, d[t]);
            d[t] = g;                       // d[] now holds adv
        }
    }

    // Pack + nontemporal store (outputs never re-read; keep L3 for inputs).
    #pragma unroll
    for (int q = 0; q < NF4; ++q) {
        const size_t o = base + 4 * q;
        f4 a4, q4;
        #pragma unroll
        for (int u = 0; u < 4; ++u) {
            const int t = 4 * q + u;
            a4[u] = d[t];
            q4[u] = d[t] + v[t];
        }
        __builtin_nontemporal_store(a4, (f4*)(adv_out + o));
        __builtin_nontemporal_store(q4, (f4*)(ret_out + o));
    }
}

extern "C" void kernel_launch(void* const* d_in, const int* in_sizes, int n_in,
                              void* d_out, int out_size, void* d_ws, size_t ws_size,
                              hipStream_t stream) {
    const float* reward     = (const float*)d_in[0];
    const int*   term       = (const int*  )d_in[1];
    const float* value      = (const float*)d_in[2];
    const float* next_value = (const float*)d_in[3];

    const int BT = in_sizes[0];
    const int B  = BT / T;

    float* adv = (float*)d_out;
    float* ret = adv + BT;

    gae_kernel<<<B / WPB, TPB, 0, stream>>>(reward, term, value, next_value, adv, ret);
}

// Round 5
// 179.312 us; speedup vs baseline: 1.7201x; 1.7201x over previous
//
#include <hip/hip_runtime.h>

// GAE backward scan. B=4096 rows, T=2048 steps.
// R6: R2's exact layout/math (the 59.6us champion: TPB=512, E=4,
// fully-coalesced 1KB wave transactions, 1 non-draining barrier)
// + persistent 4-row blocks with a 2-deep REGISTER prefetch pipeline.
// The single variable vs R2: row k+1's four dwordx4 loads (16 VGPRs)
// are issued before row k's compute, so every wave holds 4KB of reads
// in flight through its entire scan/barrier/store phase. E=4 keeps the
// prefetch set affordable (R4's E=8 version needed 32 regs/row-set ->
// 208 VGPRs, 28% occupancy, and never tested the idea cleanly).
// Expected ~80 VGPR -> 6 waves/SIMD, 3 blocks/CU resident.
// Barrier = lgkmcnt(0)+s_barrier (no vmcnt drain) + ping-pong affine
// buffers, so in-flight loads cross the per-row barrier.

constexpr float GAMMA = 0.99f;
constexpr float LMBDA = 0.95f;
constexpr float GL    = GAMMA * LMBDA;
constexpr int   T     = 2048;
constexpr int   TPB   = 512;
constexpr int   E     = T / TPB;        // 4 elements per thread
constexpr int   NW    = TPB / 64;       // 8 waves per block
constexpr int   RPB   = 4;              // rows per block (grid = 1024)

typedef float f4 __attribute__((ext_vector_type(4)));

__global__ __launch_bounds__(TPB, 6) void gae_kernel(
    const float* __restrict__ reward,
    const int*   __restrict__ term,
    const float* __restrict__ value,
    const float* __restrict__ next_value,
    float* __restrict__ adv_out,
    float* __restrict__ ret_out)
{
    const int j    = threadIdx.x;
    const int wave = j >> 6;
    const int lane = j & 63;

    __shared__ float sAf[2][NW];
    __shared__ float sBf[2][NW];

    const size_t tbase = (size_t)blockIdx.x * (RPB * T) + (size_t)j * E;

    // Prologue: row 0 loads.
    f4   rv = *(const f4*  )(reward     + tbase);
    int4 tv = *(const int4*)(term       + tbase);
    f4   vv = *(const f4*  )(value      + tbase);
    f4   nx = *(const f4*  )(next_value + tbase);

    #pragma unroll
    for (int k = 0; k < RPB; ++k) {
        // Issue row k+1's loads FIRST. Their waitcnt attaches to the
        // fold at the top of iteration k+1 -- one full compute phase
        // later -- so they stay in flight through this row's
        // scan/barrier/stores.
        f4 rv2, vv2, nx2; int4 tv2;
        if (k + 1 < RPB) {
            const size_t nb = tbase + (size_t)(k + 1) * T;
            rv2 = *(const f4*  )(reward     + nb);
            tv2 = *(const int4*)(term       + nb);
            vv2 = *(const f4*  )(value      + nb);
            nx2 = *(const f4*  )(next_value + nb);
        }

        // Fold raw row into minimal working set: c = decay, d = delta.
        // Raw regs die here; c/d are overwritten in place below.
        float c[E], d[E], v[E];
        {
            const int ti[E] = {tv.x, tv.y, tv.z, tv.w};
            #pragma unroll
            for (int u = 0; u < E; ++u) {
                const float nd = 1.f - (float)ti[u];
                v[u] = vv[u];
                c[u] = GL * nd;
                d[u] = fmaf(GAMMA * nx[u], nd, rv[u]) - vv[u];
            }
        }

        // Intra-thread backward scan, zero carry, in place:
        // d[t] <- loc[t] (local gae), c[t] <- P[t] (suffix decay product).
        {
            float g = 0.f, p = 1.f;
            #pragma unroll
            for (int t = E - 1; t >= 0; --t) {
                g = fmaf(c[t], g, d[t]);
                p *= c[t];
                d[t] = g;
                c[t] = p;
            }
        }

        // Per-wave inclusive suffix-composition scan of (A,B)=(loc[0],P[0]).
        float A = d[0], Bc = c[0];
        #pragma unroll
        for (int off = 1; off < 64; off <<= 1) {
            const float a2 = __shfl_down(A,  off, 64);
            const float b2 = __shfl_down(Bc, off, 64);
            if (lane + off < 64) {
                A  = fmaf(Bc, a2, A);
                Bc *= b2;
            }
        }

        // Publish wave affine (ping-pong by row parity: the WAR between
        // row k's reads and row k+2's writes is separated by k+1's
        // barrier, so one barrier per row suffices).
        const int pb = k & 1;
        if (lane == 0) { sAf[pb][wave] = A; sBf[pb][wave] = Bc; }

        // Exclusive suffix within the wave; lane 63 = identity.
        float eA = __shfl_down(A,  1, 64);
        float eB = __shfl_down(Bc, 1, 64);
        if (lane == 63) { eA = 0.f; eB = 1.f; }

        // Non-draining barrier: only LDS ops must land; row-(k+1)
        // global loads stay in flight (__syncthreads would vmcnt(0)).
        asm volatile("s_waitcnt lgkmcnt(0)" ::: "memory");
        __builtin_amdgcn_s_barrier();
        asm volatile("" ::: "memory");

        // Carry entering this wave = composition of wave-affines right of it.
        float wcarry = 0.f;
        #pragma unroll
        for (int w = NW - 1; w > 0; --w) {
            if (w > wave) wcarry = fmaf(sBf[pb][w], wcarry, sAf[pb][w]);
        }

        // Carry entering this thread's chunk.
        const float gin = fmaf(eB, wcarry, eA);

        // adv = loc + P*gin (d holds loc, c holds P); ret = adv + v.
        f4 a4, q4;
        #pragma unroll
        for (int t = 0; t < E; ++t) {
            const float a = fmaf(c[t], gin, d[t]);
            a4[t] = a;
            q4[t] = a + v[t];
        }
        const size_t gb = tbase + (size_t)k * T;
        __builtin_nontemporal_store(a4, (f4*)(adv_out + gb));
        __builtin_nontemporal_store(q4, (f4*)(ret_out + gb));

        if (k + 1 < RPB) { rv = rv2; tv = tv2; vv = vv2; nx = nx2; }
    }
}

extern "C" void kernel_launch(void* const* d_in, const int* in_sizes, int n_in,
                              void* d_out, int out_size, void* d_ws, size_t ws_size,
                              hipStream_t stream) {
    const float* reward     = (const float*)d_in[0];
    const int*   term       = (const int*  )d_in[1];
    const float* value      = (const float*)d_in[2];
    const float* next_value = (const float*)d_in[3];

    const int BT = in_sizes[0];
    const int B  = BT / T;

    float* adv = (float*)d_out;
    float* ret = adv + BT;

    gae_kernel<<<B / RPB, TPB, 0, stream>>>(reward, term, value, next_value, adv, ret);
}

// Round 6
// 174.761 us; speedup vs baseline: 1.7649x; 1.0260x over previous
//
#include <hip/hip_runtime.h>

// GAE backward scan. B=4096 rows, T=2048 steps.
// FINAL (= R2, the measured session best: 174.3 us bench / 58.6 us kernel,
// 2.25 TB/s HBM). Restored verbatim after R3-R6 falsified every theory
// that departed from it:
//   - pipelining (LDS-DMA @60% occ, reg @28%, reg @56%): 3x null -> BW
//     is not limited by bytes-in-flight-during-compute.
//   - occupancy (28%..65% all ~2.1-2.25 TB/s): not wave-starved.
//   - barrier removal (R5): only destroyed coalescing, never helped.
// Six structurally disjoint designs pin at 2.05-2.25 TB/s with no
// saturated counter; this shape is the empirical optimum of the family.
//
// Structure: one 512-thread block per row; thread j owns elements
// [4j, 4j+4) -> exactly ONE float4 per array per thread; every
// global_load_dwordx4 is a fully-contiguous 1 KB wave transaction.
// Scan: per-thread serial (4 elems) -> per-wave __shfl_down suffix
// composition (6 steps) -> ONE __syncthreads to combine 8 wave-affines
// via LDS. Outputs stored nontemporal.

constexpr float GAMMA = 0.99f;
constexpr float LMBDA = 0.95f;
constexpr int   T     = 2048;
constexpr int   TPB   = 512;
constexpr int   E     = T / TPB;        // 4 elements per thread
constexpr int   NW    = TPB / 64;       // 8 waves per block

typedef float f4 __attribute__((ext_vector_type(4)));

__global__ __launch_bounds__(TPB) void gae_kernel(
    const float* __restrict__ reward,
    const int*   __restrict__ term,
    const float* __restrict__ value,
    const float* __restrict__ next_value,
    float* __restrict__ adv_out,
    float* __restrict__ ret_out)
{
    const int j    = threadIdx.x;
    const int wave = j >> 6;
    const int lane = j & 63;
    const size_t base = (size_t)blockIdx.x * T + (size_t)j * E;

    // Fully-coalesced loads: one float4/int4 per array per thread.
    const float4 rv = ((const float4*)(reward     + base))[0];
    const int4   tv = ((const int4*  )(term       + base))[0];
    const float4 vv = ((const float4*)(value      + base))[0];
    const float4 nv = ((const float4*)(next_value + base))[0];

    const float r [E] = {rv.x, rv.y, rv.z, rv.w};
    const float nd[E] = {1.f - (float)tv.x, 1.f - (float)tv.y,
                         1.f - (float)tv.z, 1.f - (float)tv.w};
    const float v [E] = {vv.x, vv.y, vv.z, vv.w};
    const float nx[E] = {nv.x, nv.y, nv.z, nv.w};

    // Intra-thread backward scan, zero carry. loc[t] = local gae,
    // P[t] = product of c over [t..E-1].
    float loc[E], P[E];
    {
        float g = 0.f, p = 1.f;
        #pragma unroll
        for (int t = E - 1; t >= 0; --t) {
            const float c     = (GAMMA * LMBDA) * nd[t];
            const float delta = fmaf(GAMMA * nx[t], nd[t], r[t]) - v[t];
            g = fmaf(c, g, delta);
            p *= c;
            loc[t] = g;
            P[t]   = p;
        }
    }

    // Per-wave inclusive suffix-composition scan of (A, B) = (loc[0], P[0]).
    // (own o right)(x) = A1 + B1*(A2 + B2*x).
    float A = loc[0], Bc = P[0];
    #pragma unroll
    for (int off = 1; off < 64; off <<= 1) {
        const float a2 = __shfl_down(A,  off, 64);
        const float b2 = __shfl_down(Bc, off, 64);
        if (lane + off < 64) {
            A  = fmaf(Bc, a2, A);
            Bc *= b2;
        }
    }

    // Lane 0 holds the whole wave's affine. One barrier to share.
    __shared__ float sA[NW], sB[NW];
    if (lane == 0) { sA[wave] = A; sB[wave] = Bc; }

    // Exclusive suffix within the wave (from lane+1); lane 63 = identity.
    float eA = __shfl_down(A,  1, 64);
    float eB = __shfl_down(Bc, 1, 64);
    if (lane == 63) { eA = 0.f; eB = 1.f; }

    __syncthreads();

    // Carry entering this wave = composition of wave-affines to the right, at 0.
    float wcarry = 0.f;
    #pragma unroll
    for (int w = NW - 1; w > 0; --w) {
        if (w > wave) wcarry = fmaf(sB[w], wcarry, sA[w]);
    }

    // Carry entering this thread's chunk.
    const float gin = fmaf(eB, wcarry, eA);

    // adv[t] = loc[t] + P[t]*gin; ret = adv + v. Nontemporal stores:
    // outputs are never re-read, keep the L3 for the input arrays.
    f4 a4, q4;
    #pragma unroll
    for (int t = 0; t < E; ++t) {
        const float a = fmaf(P[t], gin, loc[t]);
        a4[t] = a;
        q4[t] = a + v[t];
    }
    __builtin_nontemporal_store(a4, (f4*)(adv_out + base));
    __builtin_nontemporal_store(q4, (f4*)(ret_out + base));
}

extern "C" void kernel_launch(void* const* d_in, const int* in_sizes, int n_in,
                              void* d_out, int out_size, void* d_ws, size_t ws_size,
                              hipStream_t stream) {
    const float* reward     = (const float*)d_in[0];
    const int*   term       = (const int*  )d_in[1];
    const float* value      = (const float*)d_in[2];
    const float* next_value = (const float*)d_in[3];

    const int BT = in_sizes[0];
    const int B  = BT / T;

    float* adv = (float*)d_out;
    float* ret = adv + BT;

    gae_kernel<<<B, TPB, 0, stream>>>(reward, term, value, next_value, adv, ret);
}